// Round 20
// baseline (295.730 us; speedup 1.0000x reference)
//
#include <hip/hip_runtime.h>
#include <hip/hip_bf16.h>
#include <math.h>

constexpr int B_N   = 32;
constexpr int L_N   = 4096;
constexpr int DM    = 256;
constexpr int DIN   = 512;
constexpr int DS    = 64;
constexpr int NH    = 8;
constexpr int HD    = 64;
constexpr int M_N   = B_N * L_N;     // 131072
constexpr int XBW   = 640;           // bf16 xbcdt row: 512 V + 64 (dead B) + 64 C
constexpr int YST   = 536;           // sY LDS stride (16B-aligned)
constexpr int AST   = 268;           // sA stride in k_inproj

typedef unsigned short u16;
typedef short s16x4 __attribute__((ext_vector_type(4)));
typedef short s16x8 __attribute__((ext_vector_type(8)));
typedef float f32x4 __attribute__((ext_vector_type(4)));
typedef unsigned short u16x8 __attribute__((ext_vector_type(8)));
typedef unsigned short u16x4 __attribute__((ext_vector_type(4)));

__device__ __forceinline__ float softplusf(float z) {
  return (z > 20.f) ? z : log1pf(expf(z));
}
__device__ __forceinline__ u16 f2bf(float f) {
  unsigned u = __float_as_uint(f);
  u += 0x7FFFu + ((u >> 16) & 1u);
  return (u16)(u >> 16);
}
__device__ __forceinline__ float bf2f(u16 u) {
  return __uint_as_float(((unsigned)u) << 16);
}
__device__ __forceinline__ s16x8 ld_frag2(const short* p) {
  s16x4 lo = *(const s16x4*)p;
  s16x4 hi = *(const s16x4*)(p + 4);
  s16x8 r;
  r[0]=lo[0]; r[1]=lo[1]; r[2]=lo[2]; r[3]=lo[3];
  r[4]=hi[0]; r[5]=hi[1]; r[6]=hi[2]; r[7]=hi[3];
  return r;
}

#define GLDS(gsrc, ldst)                                                       \
  __builtin_amdgcn_global_load_lds(                                            \
      (const __attribute__((address_space(1))) void*)(gsrc),                   \
      (__attribute__((address_space(3))) void*)(ldst), 16, 0, 0)

// ---------- Kernel 0: weight transposes -> bf16 ----------
constexpr long CW1 = 768L * 256;
constexpr long CW2 = CW1 + 256L * 512;
__global__ __launch_bounds__(256) void k_cvt(
    const float* __restrict__ Wi, const float* __restrict__ Wo,
    u16* __restrict__ WinT, u16* __restrict__ WoT) {
  for (long i = (long)blockIdx.x * 256 + threadIdx.x; i < CW2;
       i += (long)gridDim.x * 256) {
    if (i < CW1) {
      int n = (int)(i >> 8); int k = (int)(i & 255);
      WinT[i] = (n < 648) ? f2bf(Wi[(size_t)k * 648 + n]) : (u16)0;
    } else {
      long t = i - CW1; int n = (int)(t >> 9); int k = (int)(t & 511);
      WoT[t] = f2bf(Wo[(size_t)k * 256 + n]);
    }
  }
}

// ---------- Kernel 1: bf16 MFMA in-proj, 64-row tiles, 3 blocks/CU ---------
// grid (M/64). 4 waves each own a 64-col quarter of a 256-wide n-tile;
// nt = 0..2 covers N=768. LDS ~50 KB. Fused Bt/dA epilogue at nt==2.
__global__ __launch_bounds__(256) void k_inproj(
    const float* __restrict__ x, const u16* __restrict__ WinT,
    const float* __restrict__ dt_bias, const float* __restrict__ A_log,
    u16* __restrict__ xbcdt, u16* __restrict__ Bt, float* __restrict__ dAv) {
  __shared__ __align__(16) short sA[64 * AST];    // A tile [64][256]
  __shared__ __align__(16) short sB[256 * 32];    // B tile [256 n][32 k], GLDS linear
  const int tid = threadIdx.x;
  const int wave = tid >> 6, lane = tid & 63;
  const int m0 = blockIdx.x * 64;
  const int wc = wave;                            // 4 waves = 4 n-quarters
  const int fr = lane & 15, fq = lane >> 4;

  // stage A: 64 rows x 256 cols = 4096 float4s, 16 per thread
#pragma unroll
  for (int q = 0; q < 16; ++q) {
    int idx = tid + q * 256;
    int row = idx >> 6, c4 = idx & 63;
    float4 v = *(const float4*)(x + (size_t)(m0 + row) * DM + c4 * 4);
    u16x4 o = {f2bf(v.x), f2bf(v.y), f2bf(v.z), f2bf(v.w)};
    *(u16x4*)&sA[row * AST + c4 * 4] = o;
  }
  __syncthreads();

  int rowB[4], kcB[4], ldsOffB[4];
#pragma unroll
  for (int q = 0; q < 4; ++q) {
    int G = tid + q * 256;                        // 1024 x 16B = 16 KB
    rowB[q] = G >> 2; kcB[q] = G & 3;
    ldsOffB[q] = G * 8;
  }

  for (int nt = 0; nt < 3; ++nt) {
    const int n0 = nt * 256;
    f32x4 acc[4][4] = {};
    for (int k0 = 0; k0 < DM; k0 += 32) {
      if (nt || k0) __syncthreads();
#pragma unroll
      for (int q = 0; q < 4; ++q)
        GLDS(WinT + (size_t)(n0 + rowB[q]) * DM + kcB[q] * 8 + k0, sB + ldsOffB[q]);
      __syncthreads();
      const int kb = fq * 8;
      s16x8 af[4], bf[4];
#pragma unroll
      for (int i = 0; i < 4; ++i)
        af[i] = ld_frag2(&sA[(i * 16 + fr) * AST + k0 + kb]);
#pragma unroll
      for (int j = 0; j < 4; ++j)
        bf[j] = *(const s16x8*)&sB[(wc * 64 + j * 16 + fr) * 32 + kb];
#pragma unroll
      for (int i = 0; i < 4; ++i)
#pragma unroll
        for (int j = 0; j < 4; ++j)
          acc[i][j] = __builtin_amdgcn_mfma_f32_16x16x32_bf16(af[i], bf[j], acc[i][j], 0, 0, 0);
    }
    const int row_base = m0 + fq * 4;
    const int col_base = n0 + wc * 64;
    if (nt < 2 || (nt == 2 && wc == 1)) {
      // V tiles (cols 0..511) and C tile (cols 576..639)
#pragma unroll
      for (int i = 0; i < 4; ++i)
#pragma unroll
        for (int r = 0; r < 4; ++r) {
          int row = row_base + i * 16 + r;
#pragma unroll
          for (int j = 0; j < 4; ++j)
            xbcdt[(size_t)row * XBW + col_base + j * 16 + fr] = f2bf(acc[i][j][r]);
        }
    } else if (nt == 2 && wc == 0) {
      // B_ssm (cols 512..575) -> Bt[b][s][l], K(l)-major packed stores
      const int b = row_base >> 12;
      const int l_base = row_base & (L_N - 1);
#pragma unroll
      for (int i = 0; i < 4; ++i)
#pragma unroll
        for (int j = 0; j < 4; ++j) {
          int s = j * 16 + fr;
          u16x4 pk = {f2bf(acc[i][j][0]), f2bf(acc[i][j][1]),
                      f2bf(acc[i][j][2]), f2bf(acc[i][j][3])};
          *(u16x4*)&Bt[((size_t)(b * 64 + s)) * L_N + l_base + i * 16] = pk;
        }
    } else if (nt == 2 && wc == 2 && fr < 8) {
      // dt (cols 640..647, j==0) -> dA
      const float nAe = -expf(A_log[fr]);
      const float db = dt_bias[fr];
#pragma unroll
      for (int i = 0; i < 4; ++i)
#pragma unroll
        for (int r = 0; r < 4; ++r) {
          int row = row_base + i * 16 + r;
          dAv[(size_t)row * NH + fr] = softplusf(acc[i][0][r] + db) * nAe;
        }
    }
    // nt==2, wc==3: padding columns 704..767 — no store
  }
}

// ---------- Kernel 2: MFMA KV-partials, TRANSPOSED: KVp[chunk][bh][p][s] ----
__global__ __launch_bounds__(256) void k_kv(
    const u16* __restrict__ xbcdt, const u16* __restrict__ Bt,
    const float* __restrict__ dAv, float* __restrict__ KVp) {
  const int bh = blockIdx.y;
  const int b = bh >> 3, h = bh & 7;
  const int l0 = blockIdx.x * (L_N / 4);
  const int tid = threadIdx.x;
  const int wave = tid >> 6, lane = tid & 63;
  const int wr = wave >> 1, wc = wave & 1;
  const int fr = lane & 15, fq = lane >> 4;
  __shared__ short sBt[64 * 36];
  __shared__ short sVt[64 * 36];
  f32x4 acc[2][2] = {};
  const int ts = tid >> 2, tlc = tid & 3;
  const int tl = tid >> 3, tpg = tid & 7;

  for (int ks = 0; ks < L_N / 4; ks += 32) {
    u16x8 vb = *(const u16x8*)&Bt[((size_t)(b * 64 + ts)) * L_N + l0 + ks + tlc * 8];
    const int gl = b * L_N + l0 + ks + tl;
    u16x8 vv = *(const u16x8*)&xbcdt[(size_t)gl * XBW + h * HD + tpg * 8];
    const float da = dAv[(size_t)gl * NH + h];
    __syncthreads();
    *(s16x4*)&sBt[ts * 36 + tlc * 8]     = *(s16x4*)&vb;
    *(s16x4*)&sBt[ts * 36 + tlc * 8 + 4] = *((s16x4*)&vb + 1);
#pragma unroll
    for (int jj = 0; jj < 8; ++jj)
      sVt[(tpg * 8 + jj) * 36 + tl] = (short)f2bf(bf2f(vv[jj]) * da);
    __syncthreads();
    s16x8 af[2], bf[2];
#pragma unroll
    for (int i = 0; i < 2; ++i)
      af[i] = ld_frag2(&sBt[(wr * 32 + i * 16 + fr) * 36 + fq * 8]);
#pragma unroll
    for (int j = 0; j < 2; ++j)
      bf[j] = ld_frag2(&sVt[(wc * 32 + j * 16 + fr) * 36 + fq * 8]);
#pragma unroll
    for (int i = 0; i < 2; ++i)
#pragma unroll
      for (int j = 0; j < 2; ++j)
        acc[i][j] = __builtin_amdgcn_mfma_f32_16x16x32_bf16(af[i], bf[j], acc[i][j], 0, 0, 0);
  }
  float* dst = KVp + ((size_t)(blockIdx.x * 256 + bh)) * 4096;
#pragma unroll
  for (int i = 0; i < 2; ++i)
#pragma unroll
    for (int j = 0; j < 2; ++j) {
      int p = wc * 32 + j * 16 + fr;
      int s0 = wr * 32 + i * 16 + fq * 4;
      float4 v;
      v.x = acc[i][j][0]; v.y = acc[i][j][1];
      v.z = acc[i][j][2]; v.w = acc[i][j][3];
      *(float4*)&dst[p * 64 + s0] = v;
    }
}

// ---------- Kernel 2b: KVt[bh][p][s] = bf16(sum of 4 chunk partials) -------
__global__ __launch_bounds__(256) void k_kvsum(
    const float* __restrict__ KVp, u16* __restrict__ KVt) {
  const int bh = blockIdx.x;
  const int tid = threadIdx.x;
  const float* src = KVp + (size_t)bh * 4096;
#pragma unroll
  for (int q = 0; q < 4; ++q) {
    int i4 = (tid + q * 256) * 4;
    float4 v0 = *(const float4*)(src + i4);
    float4 v1 = *(const float4*)(src + 1048576 + i4);
    float4 v2 = *(const float4*)(src + 2097152 + i4);
    float4 v3 = *(const float4*)(src + 3145728 + i4);
    u16x4 o = {f2bf(v0.x + v1.x + v2.x + v3.x),
               f2bf(v0.y + v1.y + v2.y + v3.y),
               f2bf(v0.z + v1.z + v2.z + v3.z),
               f2bf(v0.w + v1.w + v2.w + v3.w)};
    *(u16x4*)&KVt[(size_t)bh * 4096 + i4] = o;
  }
}

// ---------- Kernel 3 (fused): y(all heads) -> +D*V & LN -> out = LN(y)@WoT --
__global__ __launch_bounds__(256) void k_fused(
    const u16* __restrict__ xb, const u16* __restrict__ KVt,
    const float* __restrict__ Dp, const float* __restrict__ g,
    const float* __restrict__ bt, const u16* __restrict__ WoT,
    float* __restrict__ out) {
  __shared__ __align__(16) short sC[64 * 76];
  __shared__ __align__(16) short sY[64 * YST];
  const int tid = threadIdx.x;
  const int wave = tid >> 6, lane = tid & 63;
  const int fr = lane & 15, fq = lane >> 4;
  const int m0 = blockIdx.x * 64;
  const int b = m0 >> 12;

#pragma unroll
  for (int q = 0; q < 2; ++q) {
    int idx = tid + q * 256;
    int row = idx >> 3, c8 = (idx & 7) * 8;
    u16x8 v = *(const u16x8*)&xb[(size_t)(m0 + row) * XBW + DIN + DS + c8];
    *(u16x8*)&sC[row * 76 + c8] = v;
  }

  // phase 1 (swapped operands, kt prefetch)
  {
    s16x8 ktf[2][4];
    const u16* kt0 = KVt + (size_t)(b * NH + wave) * 4096;
#pragma unroll
    for (int kk = 0; kk < 2; ++kk)
#pragma unroll
      for (int i = 0; i < 4; ++i)
        ktf[kk][i] = *(const s16x8*)&kt0[(i * 16 + fr) * 64 + kk * 32 + fq * 8];
    __syncthreads();

    s16x8 cf[2][4];
#pragma unroll
    for (int kk = 0; kk < 2; ++kk)
#pragma unroll
      for (int j = 0; j < 4; ++j)
        cf[kk][j] = *(const s16x8*)&sC[(j * 16 + fr) * 76 + kk * 32 + fq * 8];

#pragma unroll
    for (int hh = 0; hh < 2; ++hh) {
      const int h = wave + hh * 4;
      f32x4 acc[4][4] = {};
      __builtin_amdgcn_s_setprio(1);
#pragma unroll
      for (int kk = 0; kk < 2; ++kk)
#pragma unroll
        for (int i = 0; i < 4; ++i)
#pragma unroll
          for (int j = 0; j < 4; ++j)
            acc[i][j] = __builtin_amdgcn_mfma_f32_16x16x32_bf16(ktf[kk][i], cf[kk][j], acc[i][j], 0, 0, 0);
      __builtin_amdgcn_s_setprio(0);
      if (hh == 0) {
        const u16* kt1 = KVt + (size_t)(b * NH + wave + 4) * 4096;
#pragma unroll
        for (int kk = 0; kk < 2; ++kk)
#pragma unroll
          for (int i = 0; i < 4; ++i)
            ktf[kk][i] = *(const s16x8*)&kt1[(i * 16 + fr) * 64 + kk * 32 + fq * 8];
      }
#pragma unroll
      for (int i = 0; i < 4; ++i)
#pragma unroll
        for (int j = 0; j < 4; ++j) {
          u16x4 o = {f2bf(acc[i][j][0]), f2bf(acc[i][j][1]),
                     f2bf(acc[i][j][2]), f2bf(acc[i][j][3])};
          *(u16x4*)&sY[(j * 16 + fr) * YST + h * 64 + i * 16 + fq * 4] = o;
        }
    }
  }
  __syncthreads();

  // residual + stats + LayerNorm
  {
    const int row = tid >> 2, seg4 = tid & 3;
    const u16* vrow = xb + (size_t)(m0 + row) * XBW;
    float s = 0.f, q = 0.f;
#pragma unroll
    for (int c = 0; c < 16; ++c) {
      int k0 = seg4 * 8 + c * 32;
      const float ds = Dp[c >> 1];
      u16x8 v = *(const u16x8*)&sY[row * YST + k0];
      u16x8 w = *(const u16x8*)(vrow + k0);
      u16x8 o;
#pragma unroll
      for (int jj = 0; jj < 8; ++jj) {
        float f = bf2f(v[jj]) + ds * bf2f(w[jj]);
        s += f; q += f * f;
        o[jj] = f2bf(f);
      }
      *(u16x8*)&sY[row * YST + k0] = o;
    }
    s += __shfl_xor(s, 1); q += __shfl_xor(q, 1);
    s += __shfl_xor(s, 2); q += __shfl_xor(q, 2);
    const float mu = s / DIN;
    const float rstd = rsqrtf(q / DIN - mu * mu + 1e-5f);
#pragma unroll
    for (int c = 0; c < 16; ++c) {
      int k0 = seg4 * 8 + c * 32;
      u16x8 v = *(const u16x8*)&sY[row * YST + k0];
      float4 g0 = *(const float4*)(g + k0);
      float4 g1 = *(const float4*)(g + k0 + 4);
      float4 b0 = *(const float4*)(bt + k0);
      float4 b1 = *(const float4*)(bt + k0 + 4);
      u16x8 o;
      o[0] = f2bf((bf2f(v[0]) - mu) * rstd * g0.x + b0.x);
      o[1] = f2bf((bf2f(v[1]) - mu) * rstd * g0.y + b0.y);
      o[2] = f2bf((bf2f(v[2]) - mu) * rstd * g0.z + b0.z);
      o[3] = f2bf((bf2f(v[3]) - mu) * rstd * g0.w + b0.w);
      o[4] = f2bf((bf2f(v[4]) - mu) * rstd * g1.x + b1.x);
      o[5] = f2bf((bf2f(v[5]) - mu) * rstd * g1.y + b1.y);
      o[6] = f2bf((bf2f(v[6]) - mu) * rstd * g1.z + b1.z);
      o[7] = f2bf((bf2f(v[7]) - mu) * rstd * g1.w + b1.w);
      *(u16x8*)&sY[row * YST + k0] = o;
    }
  }
  __syncthreads();

  // phase 2: software-pipelined WoT fragments
  {
    const u16* wb = WoT + (size_t)(wave * 64 + fr) * DIN + fq * 8;
    f32x4 acc2[4][4] = {};
    s16x8 bfc[4], bfn[4];
#pragma unroll
    for (int j = 0; j < 4; ++j)
      bfc[j] = *(const s16x8*)&wb[(size_t)(j * 16) * DIN];
#pragma unroll
    for (int kk = 0; kk < 16; ++kk) {
      if (kk < 15) {
#pragma unroll
        for (int j = 0; j < 4; ++j)
          bfn[j] = *(const s16x8*)&wb[(size_t)(j * 16) * DIN + (kk + 1) * 32];
      }
      s16x8 af2[4];
#pragma unroll
      for (int i = 0; i < 4; ++i)
        af2[i] = *(const s16x8*)&sY[(i * 16 + fr) * YST + kk * 32 + fq * 8];
      __builtin_amdgcn_s_setprio(1);
#pragma unroll
      for (int i = 0; i < 4; ++i)
#pragma unroll
        for (int j = 0; j < 4; ++j)
          acc2[i][j] = __builtin_amdgcn_mfma_f32_16x16x32_bf16(af2[i], bfc[j], acc2[i][j], 0, 0, 0);
      __builtin_amdgcn_s_setprio(0);
#pragma unroll
      for (int j = 0; j < 4; ++j) bfc[j] = bfn[j];
    }
#pragma unroll
    for (int i = 0; i < 4; ++i)
#pragma unroll
      for (int r = 0; r < 4; ++r) {
        int row = m0 + i * 16 + fq * 4 + r;
#pragma unroll
        for (int j = 0; j < 4; ++j)
          out[(size_t)row * DM + wave * 64 + j * 16 + fr] = acc2[i][j][r];
      }
  }
}

extern "C" void kernel_launch(void* const* d_in, const int* in_sizes, int n_in,
                              void* d_out, int out_size, void* d_ws, size_t ws_size,
                              hipStream_t stream) {
  const float* x       = (const float*)d_in[0];
  const float* W_in    = (const float*)d_in[1];
  const float* dt_bias = (const float*)d_in[2];
  const float* A_log   = (const float*)d_in[3];
  const float* D_param = (const float*)d_in[4];
  const float* gamma   = (const float*)d_in[5];
  const float* beta    = (const float*)d_in[6];
  const float* W_out   = (const float*)d_in[7];
  float* out = (float*)d_out;

  u16* ws    = (u16*)d_ws;
  u16* WinT  = ws;                                    // 768*256 bf16
  u16* WoT   = WinT + 768L * 256;                     // 256*512 bf16
  u16* xbcdt = WoT + 256L * 512;                      // M*640 bf16
  u16* Bt    = xbcdt + (size_t)M_N * XBW;             // 32*64*4096 bf16
  float* dAv = (float*)(Bt + (size_t)B_N * 64 * L_N); // M*8 fp32
  float* KVp = dAv + (size_t)M_N * NH;                // 4*256*4096 fp32
  u16* KVt   = (u16*)(KVp + 4L * 256 * 4096);         // 256*4096 bf16

  k_cvt    <<<256, 256, 0, stream>>>(W_in, W_out, WinT, WoT);
  k_inproj <<<M_N / 64, 256, 0, stream>>>(x, WinT, dt_bias, A_log, xbcdt, Bt, dAv);
  k_kv     <<<dim3(4, B_N * NH), 256, 0, stream>>>(xbcdt, Bt, dAv, KVp);
  k_kvsum  <<<B_N * NH, 256, 0, stream>>>(KVp, KVt);
  k_fused  <<<M_N / 64, 256, 0, stream>>>(xbcdt, KVt, D_param, gamma, beta, WoT, out);
}

// Round 21
// 277.478 us; speedup vs baseline: 1.0658x; 1.0658x over previous
//
#include <hip/hip_runtime.h>
#include <hip/hip_bf16.h>
#include <math.h>

constexpr int B_N   = 32;
constexpr int L_N   = 4096;
constexpr int DM    = 256;
constexpr int DIN   = 512;
constexpr int DS    = 64;
constexpr int NH    = 8;
constexpr int HD    = 64;
constexpr int M_N   = B_N * L_N;     // 131072
constexpr int XBW   = 640;           // bf16 xbcdt row: 512 V + 64 (dead B) + 64 C
constexpr int YST   = 536;           // sY LDS stride (16B-aligned)
constexpr int AST   = 268;           // sA stride in k_inproj

typedef unsigned short u16;
typedef short s16x4 __attribute__((ext_vector_type(4)));
typedef short s16x8 __attribute__((ext_vector_type(8)));
typedef float f32x4 __attribute__((ext_vector_type(4)));
typedef unsigned short u16x8 __attribute__((ext_vector_type(8)));
typedef unsigned short u16x4 __attribute__((ext_vector_type(4)));

__device__ __forceinline__ float softplusf(float z) {
  return (z > 20.f) ? z : log1pf(expf(z));
}
__device__ __forceinline__ u16 f2bf(float f) {
  unsigned u = __float_as_uint(f);
  u += 0x7FFFu + ((u >> 16) & 1u);
  return (u16)(u >> 16);
}
__device__ __forceinline__ float bf2f(u16 u) {
  return __uint_as_float(((unsigned)u) << 16);
}
__device__ __forceinline__ s16x8 ld_frag2(const short* p) {
  s16x4 lo = *(const s16x4*)p;
  s16x4 hi = *(const s16x4*)(p + 4);
  s16x8 r;
  r[0]=lo[0]; r[1]=lo[1]; r[2]=lo[2]; r[3]=lo[3];
  r[4]=hi[0]; r[5]=hi[1]; r[6]=hi[2]; r[7]=hi[3];
  return r;
}

#define GLDS(gsrc, ldst)                                                       \
  __builtin_amdgcn_global_load_lds(                                            \
      (const __attribute__((address_space(1))) void*)(gsrc),                   \
      (__attribute__((address_space(3))) void*)(ldst), 16, 0, 0)

// ---------- Kernel 0: weight transposes -> bf16 ----------
constexpr long CW1 = 768L * 256;
constexpr long CW2 = CW1 + 256L * 512;
__global__ __launch_bounds__(256) void k_cvt(
    const float* __restrict__ Wi, const float* __restrict__ Wo,
    u16* __restrict__ WinT, u16* __restrict__ WoT) {
  for (long i = (long)blockIdx.x * 256 + threadIdx.x; i < CW2;
       i += (long)gridDim.x * 256) {
    if (i < CW1) {
      int n = (int)(i >> 8); int k = (int)(i & 255);
      WinT[i] = (n < 648) ? f2bf(Wi[(size_t)k * 648 + n]) : (u16)0;
    } else {
      long t = i - CW1; int n = (int)(t >> 9); int k = (int)(t & 511);
      WoT[t] = f2bf(Wo[(size_t)k * 256 + n]);
    }
  }
}

// ---------- Kernel 1: bf16 MFMA in-proj + fused Bt epilogue (validated) ----
__global__ __launch_bounds__(256) void k_inproj(
    const float* __restrict__ x, const u16* __restrict__ WinT,
    const float* __restrict__ dt_bias, const float* __restrict__ A_log,
    u16* __restrict__ xbcdt, u16* __restrict__ Bt, float* __restrict__ dAv) {
  __shared__ __align__(16) short sA[128 * AST];
  __shared__ __align__(16) short sB[128 * 32];
  const int tid = threadIdx.x;
  const int wave = tid >> 6, lane = tid & 63;
  const int m0 = blockIdx.x * 128;
  const int wr = wave >> 1, wc = wave & 1;
  const int fr = lane & 15, fq = lane >> 4;

#pragma unroll
  for (int q = 0; q < 32; ++q) {
    int idx = tid + q * 256;
    int row = idx >> 6, c4 = idx & 63;
    float4 v = *(const float4*)(x + (size_t)(m0 + row) * DM + c4 * 4);
    u16x4 o = {f2bf(v.x), f2bf(v.y), f2bf(v.z), f2bf(v.w)};
    *(u16x4*)&sA[row * AST + c4 * 4] = o;
  }
  __syncthreads();

  int rowB[2], kcB[2], ldsOffB[2];
#pragma unroll
  for (int q = 0; q < 2; ++q) {
    int G = wave * 128 + q * 64 + lane;
    rowB[q] = G >> 2; kcB[q] = G & 3;
    ldsOffB[q] = G * 8;
  }

  for (int nt = 0; nt < 6; ++nt) {
    const int n0 = nt * 128;
    f32x4 acc[4][4] = {};
    for (int k0 = 0; k0 < DM; k0 += 32) {
      if (nt || k0) __syncthreads();
#pragma unroll
      for (int q = 0; q < 2; ++q)
        GLDS(WinT + (size_t)(n0 + rowB[q]) * DM + kcB[q] * 8 + k0, sB + ldsOffB[q]);
      __syncthreads();
      const int kb = fq * 8;
      s16x8 af[4], bf[4];
#pragma unroll
      for (int i = 0; i < 4; ++i)
        af[i] = ld_frag2(&sA[(wr * 64 + i * 16 + fr) * AST + k0 + kb]);
#pragma unroll
      for (int j = 0; j < 4; ++j)
        bf[j] = *(const s16x8*)&sB[(wc * 64 + j * 16 + fr) * 32 + kb];
#pragma unroll
      for (int i = 0; i < 4; ++i)
#pragma unroll
        for (int j = 0; j < 4; ++j)
          acc[i][j] = __builtin_amdgcn_mfma_f32_16x16x32_bf16(af[i], bf[j], acc[i][j], 0, 0, 0);
    }
    const int row_base = m0 + wr * 64 + fq * 4;
    if (n0 < 512 || (nt == 4 && wc == 1)) {
      const int col_base = n0 + wc * 64;
#pragma unroll
      for (int i = 0; i < 4; ++i)
#pragma unroll
        for (int r = 0; r < 4; ++r) {
          int row = row_base + i * 16 + r;
#pragma unroll
          for (int j = 0; j < 4; ++j)
            xbcdt[(size_t)row * XBW + col_base + j * 16 + fr] = f2bf(acc[i][j][r]);
        }
    } else if (nt == 4) {
      const int b = row_base >> 12;
      const int l_base = (row_base & (L_N - 1));
#pragma unroll
      for (int i = 0; i < 4; ++i)
#pragma unroll
        for (int j = 0; j < 4; ++j) {
          int s = j * 16 + fr;
          u16x4 pk = {f2bf(acc[i][j][0]), f2bf(acc[i][j][1]),
                      f2bf(acc[i][j][2]), f2bf(acc[i][j][3])};
          *(u16x4*)&Bt[((size_t)(b * 64 + s)) * L_N + l_base + i * 16] = pk;
        }
    } else if (nt == 5 && wc == 0 && fr < 8) {
      const float nAe = -expf(A_log[fr]);
      const float db = dt_bias[fr];
#pragma unroll
      for (int i = 0; i < 4; ++i)
#pragma unroll
        for (int r = 0; r < 4; ++r) {
          int row = row_base + i * 16 + r;
          dAv[(size_t)row * NH + fr] = softplusf(acc[i][0][r] + db) * nAe;
        }
    }
  }
}

// ---------- Kernel 2: MFMA KV-partials, TRANSPOSED: KVp[chunk][bh][p][s] ----
__global__ __launch_bounds__(256) void k_kv(
    const u16* __restrict__ xbcdt, const u16* __restrict__ Bt,
    const float* __restrict__ dAv, float* __restrict__ KVp) {
  const int bh = blockIdx.y;
  const int b = bh >> 3, h = bh & 7;
  const int l0 = blockIdx.x * (L_N / 4);
  const int tid = threadIdx.x;
  const int wave = tid >> 6, lane = tid & 63;
  const int wr = wave >> 1, wc = wave & 1;
  const int fr = lane & 15, fq = lane >> 4;
  __shared__ short sBt[64 * 36];
  __shared__ short sVt[64 * 36];
  f32x4 acc[2][2] = {};
  const int ts = tid >> 2, tlc = tid & 3;
  const int tl = tid >> 3, tpg = tid & 7;

  for (int ks = 0; ks < L_N / 4; ks += 32) {
    u16x8 vb = *(const u16x8*)&Bt[((size_t)(b * 64 + ts)) * L_N + l0 + ks + tlc * 8];
    const int gl = b * L_N + l0 + ks + tl;
    u16x8 vv = *(const u16x8*)&xbcdt[(size_t)gl * XBW + h * HD + tpg * 8];
    const float da = dAv[(size_t)gl * NH + h];
    __syncthreads();
    *(s16x4*)&sBt[ts * 36 + tlc * 8]     = *(s16x4*)&vb;
    *(s16x4*)&sBt[ts * 36 + tlc * 8 + 4] = *((s16x4*)&vb + 1);
#pragma unroll
    for (int jj = 0; jj < 8; ++jj)
      sVt[(tpg * 8 + jj) * 36 + tl] = (short)f2bf(bf2f(vv[jj]) * da);
    __syncthreads();
    s16x8 af[2], bf[2];
#pragma unroll
    for (int i = 0; i < 2; ++i)
      af[i] = ld_frag2(&sBt[(wr * 32 + i * 16 + fr) * 36 + fq * 8]);
#pragma unroll
    for (int j = 0; j < 2; ++j)
      bf[j] = ld_frag2(&sVt[(wc * 32 + j * 16 + fr) * 36 + fq * 8]);
#pragma unroll
    for (int i = 0; i < 2; ++i)
#pragma unroll
      for (int j = 0; j < 2; ++j)
        acc[i][j] = __builtin_amdgcn_mfma_f32_16x16x32_bf16(af[i], bf[j], acc[i][j], 0, 0, 0);
  }
  float* dst = KVp + ((size_t)(blockIdx.x * 256 + bh)) * 4096;
#pragma unroll
  for (int i = 0; i < 2; ++i)
#pragma unroll
    for (int j = 0; j < 2; ++j) {
      int p = wc * 32 + j * 16 + fr;
      int s0 = wr * 32 + i * 16 + fq * 4;
      float4 v;
      v.x = acc[i][j][0]; v.y = acc[i][j][1];
      v.z = acc[i][j][2]; v.w = acc[i][j][3];
      *(float4*)&dst[p * 64 + s0] = v;
    }
}

// ---------- Kernel 2b: KVt[bh][p][s] = bf16(sum of 4 chunk partials) -------
__global__ __launch_bounds__(256) void k_kvsum(
    const float* __restrict__ KVp, u16* __restrict__ KVt) {
  const int bh = blockIdx.x;
  const int tid = threadIdx.x;
  const float* src = KVp + (size_t)bh * 4096;
#pragma unroll
  for (int q = 0; q < 4; ++q) {
    int i4 = (tid + q * 256) * 4;
    float4 v0 = *(const float4*)(src + i4);
    float4 v1 = *(const float4*)(src + 1048576 + i4);
    float4 v2 = *(const float4*)(src + 2097152 + i4);
    float4 v3 = *(const float4*)(src + 3145728 + i4);
    u16x4 o = {f2bf(v0.x + v1.x + v2.x + v3.x),
               f2bf(v0.y + v1.y + v2.y + v3.y),
               f2bf(v0.z + v1.z + v2.z + v3.z),
               f2bf(v0.w + v1.w + v2.w + v3.w)};
    *(u16x4*)&KVt[(size_t)bh * 4096 + i4] = o;
  }
}

// ---------- Kernel 3 (fused): y(all heads) -> +D*V & LN -> out = LN(y)@WoT --
__global__ __launch_bounds__(256) void k_fused(
    const u16* __restrict__ xb, const u16* __restrict__ KVt,
    const float* __restrict__ Dp, const float* __restrict__ g,
    const float* __restrict__ bt, const u16* __restrict__ WoT,
    float* __restrict__ out) {
  __shared__ __align__(16) short sC[64 * 76];
  __shared__ __align__(16) short sY[64 * YST];
  const int tid = threadIdx.x;
  const int wave = tid >> 6, lane = tid & 63;
  const int fr = lane & 15, fq = lane >> 4;
  const int m0 = blockIdx.x * 64;
  const int b = m0 >> 12;

#pragma unroll
  for (int q = 0; q < 2; ++q) {
    int idx = tid + q * 256;
    int row = idx >> 3, c8 = (idx & 7) * 8;
    u16x8 v = *(const u16x8*)&xb[(size_t)(m0 + row) * XBW + DIN + DS + c8];
    *(u16x8*)&sC[row * 76 + c8] = v;
  }

  // phase 1 (swapped operands, kt prefetch)
  {
    s16x8 ktf[2][4];
    const u16* kt0 = KVt + (size_t)(b * NH + wave) * 4096;
#pragma unroll
    for (int kk = 0; kk < 2; ++kk)
#pragma unroll
      for (int i = 0; i < 4; ++i)
        ktf[kk][i] = *(const s16x8*)&kt0[(i * 16 + fr) * 64 + kk * 32 + fq * 8];
    __syncthreads();

    s16x8 cf[2][4];
#pragma unroll
    for (int kk = 0; kk < 2; ++kk)
#pragma unroll
      for (int j = 0; j < 4; ++j)
        cf[kk][j] = *(const s16x8*)&sC[(j * 16 + fr) * 76 + kk * 32 + fq * 8];

#pragma unroll
    for (int hh = 0; hh < 2; ++hh) {
      const int h = wave + hh * 4;
      f32x4 acc[4][4] = {};
      __builtin_amdgcn_s_setprio(1);
#pragma unroll
      for (int kk = 0; kk < 2; ++kk)
#pragma unroll
        for (int i = 0; i < 4; ++i)
#pragma unroll
          for (int j = 0; j < 4; ++j)
            acc[i][j] = __builtin_amdgcn_mfma_f32_16x16x32_bf16(ktf[kk][i], cf[kk][j], acc[i][j], 0, 0, 0);
      __builtin_amdgcn_s_setprio(0);
      if (hh == 0) {
        const u16* kt1 = KVt + (size_t)(b * NH + wave + 4) * 4096;
#pragma unroll
        for (int kk = 0; kk < 2; ++kk)
#pragma unroll
          for (int i = 0; i < 4; ++i)
            ktf[kk][i] = *(const s16x8*)&kt1[(i * 16 + fr) * 64 + kk * 32 + fq * 8];
      }
#pragma unroll
      for (int i = 0; i < 4; ++i)
#pragma unroll
        for (int j = 0; j < 4; ++j) {
          u16x4 o = {f2bf(acc[i][j][0]), f2bf(acc[i][j][1]),
                     f2bf(acc[i][j][2]), f2bf(acc[i][j][3])};
          *(u16x4*)&sY[(j * 16 + fr) * YST + h * 64 + i * 16 + fq * 4] = o;
        }
    }
  }
  __syncthreads();

  // residual + stats + LayerNorm
  {
    const int row = tid >> 2, seg4 = tid & 3;
    const u16* vrow = xb + (size_t)(m0 + row) * XBW;
    float s = 0.f, q = 0.f;
#pragma unroll
    for (int c = 0; c < 16; ++c) {
      int k0 = seg4 * 8 + c * 32;
      const float ds = Dp[c >> 1];
      u16x8 v = *(const u16x8*)&sY[row * YST + k0];
      u16x8 w = *(const u16x8*)(vrow + k0);
      u16x8 o;
#pragma unroll
      for (int jj = 0; jj < 8; ++jj) {
        float f = bf2f(v[jj]) + ds * bf2f(w[jj]);
        s += f; q += f * f;
        o[jj] = f2bf(f);
      }
      *(u16x8*)&sY[row * YST + k0] = o;
    }
    s += __shfl_xor(s, 1); q += __shfl_xor(q, 1);
    s += __shfl_xor(s, 2); q += __shfl_xor(q, 2);
    const float mu = s / DIN;
    const float rstd = rsqrtf(q / DIN - mu * mu + 1e-5f);
#pragma unroll
    for (int c = 0; c < 16; ++c) {
      int k0 = seg4 * 8 + c * 32;
      u16x8 v = *(const u16x8*)&sY[row * YST + k0];
      float4 g0 = *(const float4*)(g + k0);
      float4 g1 = *(const float4*)(g + k0 + 4);
      float4 b0 = *(const float4*)(bt + k0);
      float4 b1 = *(const float4*)(bt + k0 + 4);
      u16x8 o;
      o[0] = f2bf((bf2f(v[0]) - mu) * rstd * g0.x + b0.x);
      o[1] = f2bf((bf2f(v[1]) - mu) * rstd * g0.y + b0.y);
      o[2] = f2bf((bf2f(v[2]) - mu) * rstd * g0.z + b0.z);
      o[3] = f2bf((bf2f(v[3]) - mu) * rstd * g0.w + b0.w);
      o[4] = f2bf((bf2f(v[4]) - mu) * rstd * g1.x + b1.x);
      o[5] = f2bf((bf2f(v[5]) - mu) * rstd * g1.y + b1.y);
      o[6] = f2bf((bf2f(v[6]) - mu) * rstd * g1.z + b1.z);
      o[7] = f2bf((bf2f(v[7]) - mu) * rstd * g1.w + b1.w);
      *(u16x8*)&sY[row * YST + k0] = o;
    }
  }
  __syncthreads();

  // phase 2: software-pipelined WoT fragments
  {
    const u16* wb = WoT + (size_t)(wave * 64 + fr) * DIN + fq * 8;
    f32x4 acc2[4][4] = {};
    s16x8 bfc[4], bfn[4];
#pragma unroll
    for (int j = 0; j < 4; ++j)
      bfc[j] = *(const s16x8*)&wb[(size_t)(j * 16) * DIN];
#pragma unroll
    for (int kk = 0; kk < 16; ++kk) {
      if (kk < 15) {
#pragma unroll
        for (int j = 0; j < 4; ++j)
          bfn[j] = *(const s16x8*)&wb[(size_t)(j * 16) * DIN + (kk + 1) * 32];
      }
      s16x8 af2[4];
#pragma unroll
      for (int i = 0; i < 4; ++i)
        af2[i] = *(const s16x8*)&sY[(i * 16 + fr) * YST + kk * 32 + fq * 8];
      __builtin_amdgcn_s_setprio(1);
#pragma unroll
      for (int i = 0; i < 4; ++i)
#pragma unroll
        for (int j = 0; j < 4; ++j)
          acc2[i][j] = __builtin_amdgcn_mfma_f32_16x16x32_bf16(af2[i], bfc[j], acc2[i][j], 0, 0, 0);
      __builtin_amdgcn_s_setprio(0);
#pragma unroll
      for (int j = 0; j < 4; ++j) bfc[j] = bfn[j];
    }
#pragma unroll
    for (int i = 0; i < 4; ++i)
#pragma unroll
      for (int r = 0; r < 4; ++r) {
        int row = m0 + i * 16 + fq * 4 + r;
#pragma unroll
        for (int j = 0; j < 4; ++j)
          out[(size_t)row * DM + wave * 64 + j * 16 + fr] = acc2[i][j][r];
      }
  }
}

extern "C" void kernel_launch(void* const* d_in, const int* in_sizes, int n_in,
                              void* d_out, int out_size, void* d_ws, size_t ws_size,
                              hipStream_t stream) {
  const float* x       = (const float*)d_in[0];
  const float* W_in    = (const float*)d_in[1];
  const float* dt_bias = (const float*)d_in[2];
  const float* A_log   = (const float*)d_in[3];
  const float* D_param = (const float*)d_in[4];
  const float* gamma   = (const float*)d_in[5];
  const float* beta    = (const float*)d_in[6];
  const float* W_out   = (const float*)d_in[7];
  float* out = (float*)d_out;

  u16* ws    = (u16*)d_ws;
  u16* WinT  = ws;                                    // 768*256 bf16
  u16* WoT   = WinT + 768L * 256;                     // 256*512 bf16
  u16* xbcdt = WoT + 256L * 512;                      // M*640 bf16
  u16* Bt    = xbcdt + (size_t)M_N * XBW;             // 32*64*4096 bf16
  float* dAv = (float*)(Bt + (size_t)B_N * 64 * L_N); // M*8 fp32
  float* KVp = dAv + (size_t)M_N * NH;                // 4*256*4096 fp32
  u16* KVt   = (u16*)(KVp + 4L * 256 * 4096);         // 256*4096 bf16

  k_cvt    <<<256, 256, 0, stream>>>(W_in, W_out, WinT, WoT);
  k_inproj <<<M_N / 128, 256, 0, stream>>>(x, WinT, dt_bias, A_log, xbcdt, Bt, dAv);
  k_kv     <<<dim3(4, B_N * NH), 256, 0, stream>>>(xbcdt, Bt, dAv, KVp);
  k_kvsum  <<<B_N * NH, 256, 0, stream>>>(KVp, KVt);
  k_fused  <<<M_N / 64, 256, 0, stream>>>(xbcdt, KVt, D_param, gamma, beta, WoT, out);
}